// Round 14
// baseline (274.182 us; speedup 1.0000x reference)
//
#include <hip/hip_runtime.h>
#include <hip/hip_bf16.h>

#define NROWS 16384
#define DIM   256
#define SEGS  8
#define BN    128                     // staged tile: 128 cols x 256 k (fp8) = 32 KB
#define NT    ((NROWS / SEGS) / BN)   // 16 tiles per segment
#define INVT  14.285714285714286f
#define C1f   20.60992915555662f      // log2(e)/0.07 ; A is pre-scaled by this
#define LN2f  0.6931471805599453f

typedef __attribute__((ext_vector_type(8)))  int   int8v;    // fp8 A/B fragment (32 bytes)
typedef __attribute__((ext_vector_type(16))) float f32x16;   // 32x32 MFMA accumulator

#define SCALE1 0x7F7F7F7F   // E8M0 = 1.0 in every byte (opsel-proof)

// Kernel 1: L2-normalize (fp32); emit fp8 e4m3 A (row-major, xC1) and fp8 B in the
// DMA staging layout (NO xor swizzle -- DMA writes are linear/conflict-free and
// reads are contiguous; swizzle was vestigial), plus exact fp32 diagonal.
// B layout (16B chunks): chunk(col,kcb) = (col>>7)*2048 + ((col>>6)&1)*1024
//                                        + kcb*64 + (col&63)
__global__ __launch_bounds__(256) void norm_diag_kernel(
    const float* __restrict__ fl, const float* __restrict__ fg,
    unsigned char* __restrict__ A, unsigned char* __restrict__ B,
    float* __restrict__ diag, float* __restrict__ out)
{
    int tid  = threadIdx.x;
    int wave = tid >> 6, lane = tid & 63;
    int row  = blockIdx.x * 4 + wave;
    if (blockIdx.x == 0 && tid == 0) out[0] = 0.0f;   // zero accumulator for final atomicAdd

    float4 xl = ((const float4*)(fl + (size_t)row * DIM))[lane];
    float4 xg = ((const float4*)(fg + (size_t)row * DIM))[lane];
    float ssl = xl.x*xl.x + xl.y*xl.y + xl.z*xl.z + xl.w*xl.w;
    float ssg = xg.x*xg.x + xg.y*xg.y + xg.z*xg.z + xg.w*xg.w;
    for (int m = 1; m < 64; m <<= 1) {
        ssl += __shfl_xor(ssl, m, 64);
        ssg += __shfl_xor(ssg, m, 64);
    }
    float il = 1.0f / fmaxf(sqrtf(ssl), 1e-12f);
    float ig = 1.0f / fmaxf(sqrtf(ssg), 1e-12f);
    float nl0 = xl.x*il, nl1 = xl.y*il, nl2 = xl.z*il, nl3 = xl.w*il;
    float ng0 = xg.x*ig, ng1 = xg.y*ig, ng2 = xg.z*ig, ng3 = xg.w*ig;

    int pa = __builtin_amdgcn_cvt_pk_fp8_f32(nl0 * C1f, nl1 * C1f, 0, false);
    pa     = __builtin_amdgcn_cvt_pk_fp8_f32(nl2 * C1f, nl3 * C1f, pa, true);
    int pb = __builtin_amdgcn_cvt_pk_fp8_f32(ng0, ng1, 0, false);
    pb     = __builtin_amdgcn_cvt_pk_fp8_f32(ng2, ng3, pb, true);
    ((int*)(A + (size_t)row * DIM))[lane] = pa;   // A row-major

    {   // B in staging layout (linear, no xor)
        int kcb = lane >> 2;          // 16B chunk along K (0..15)
        int b4  = lane & 3;           // dword within chunk
        unsigned chunk = (unsigned)((row >> 7) * 2048 + ((row >> 6) & 1) * 1024
                                    + kcb * 64 + (row & 63));
        ((int*)B)[chunk * 4 + b4] = pb;
    }

    float d = nl0*ng0 + nl1*ng1 + nl2*ng2 + nl3*ng3;   // exact fp32 diagonal
    for (int m = 1; m < 64; m <<= 1) d += __shfl_xor(d, m, 64);
    if (lane == 0) diag[row] = d;
}

// ---- macros for the fully-unrolled, register-named inner pipeline ----
#define MK8(v, lo, hi) { v[0]=lo.x; v[1]=lo.y; v[2]=lo.z; v[3]=lo.w; \
                         v[4]=hi.x; v[5]=hi.y; v[6]=hi.z; v[7]=hi.w; }
#define MFMA1(dst, a, b, cin) \
    dst = __builtin_amdgcn_mfma_scale_f32_32x32x64_f8f6f4(a, b, cin, 0, 0, 0, SCALE1, 0, SCALE1)
#define E4(lvv, pv, r0) \
    lvv[r0+0] += __builtin_amdgcn_exp2f(pv[r0+0]); \
    lvv[r0+1] += __builtin_amdgcn_exp2f(pv[r0+1]); \
    lvv[r0+2] += __builtin_amdgcn_exp2f(pv[r0+2]); \
    lvv[r0+3] += __builtin_amdgcn_exp2f(pv[r0+3]);

// One 64x32 unit at compile-time LDS offset OFFC: 8 ds_read_b128 (imm offsets,
// single base VGPR), then MFMA(current) 1:1-interleaved with exp2(previous unit).
#define UNIT(AC0, AC1, PV0, PV1, OFFC) { \
    int4 l0 = *(const int4*)&bt[vb + (OFFC) +     0]; \
    int4 h0 = *(const int4*)&bt[vb + (OFFC) +  1024]; \
    int4 l1 = *(const int4*)&bt[vb + (OFFC) +  4096]; \
    int4 h1 = *(const int4*)&bt[vb + (OFFC) +  5120]; \
    int4 l2 = *(const int4*)&bt[vb + (OFFC) +  8192]; \
    int4 h2 = *(const int4*)&bt[vb + (OFFC) +  9216]; \
    int4 l3 = *(const int4*)&bt[vb + (OFFC) + 12288]; \
    int4 h3 = *(const int4*)&bt[vb + (OFFC) + 13312]; \
    int8v b0, b1, b2, b3; \
    MK8(b0, l0, h0) MK8(b1, l1, h1) MK8(b2, l2, h2) MK8(b3, l3, h3) \
    MFMA1(AC0, af00, b0, Z);   E4(lv0, PV0, 0) \
    MFMA1(AC1, af10, b0, Z);   E4(lv1, PV1, 0) \
    MFMA1(AC0, af01, b1, AC0); E4(lv0, PV0, 4) \
    MFMA1(AC1, af11, b1, AC1); E4(lv1, PV1, 4) \
    MFMA1(AC0, af02, b2, AC0); E4(lv0, PV0, 8) \
    MFMA1(AC1, af12, b2, AC1); E4(lv1, PV1, 8) \
    MFMA1(AC0, af03, b3, AC0); E4(lv0, PV0, 12) \
    MFMA1(AC1, af13, b3, AC1); E4(lv1, PV1, 12) \
}

// Kernel 2: fused sim-GEMM + fixed-max sumexp, MX-fp8 32x32x64.
// R6/R10 frame (DMA prefetch, one barrier/tile, ping-pong acc) with:
//  - de-XORed LDS layout -> every ds_read is base + 16-bit immediate (0 addr VALU)
//  - instruction-granular MFMA<->exp2 interleave on named registers (no arrays)
__global__ __launch_bounds__(256, 2) void sim_lse_kernel(
    const unsigned char* __restrict__ A, const unsigned char* __restrict__ B,
    float* __restrict__ lpart)
{
    __shared__ __align__(16) unsigned char bt[2 * BN * DIM];   // 2 x 32 KB double buffer

    int tid  = threadIdx.x;
    int lane = tid & 63;
    int l31  = lane & 31, half = lane >> 5;
    int wave = tid >> 6;
    int seg  = blockIdx.x;
    int rowBase = blockIdx.y * 256 + wave * 64;

    // Single LDS read base: col=l31 (+512 for c=1 via immediate), kcb base = half*2
    unsigned vb = (unsigned)(l31 * 16 + half * 2048);

    // Preload A fragments (row-major): lane(l31,half) holds A[m=l31][k=kk*64+half*32+0..31]
    int8v af00, af01, af02, af03, af10, af11, af12, af13;
    {
        const unsigned char* ap0 = A + (size_t)(rowBase + l31) * DIM + half * 32;
        const unsigned char* ap1 = A + (size_t)(rowBase + 32 + l31) * DIM + half * 32;
        int4 lo, hi;
        lo = *(const int4*)(ap0 +   0); hi = *(const int4*)(ap0 +  16); MK8(af00, lo, hi)
        lo = *(const int4*)(ap0 +  64); hi = *(const int4*)(ap0 +  80); MK8(af01, lo, hi)
        lo = *(const int4*)(ap0 + 128); hi = *(const int4*)(ap0 + 144); MK8(af02, lo, hi)
        lo = *(const int4*)(ap0 + 192); hi = *(const int4*)(ap0 + 208); MK8(af03, lo, hi)
        lo = *(const int4*)(ap1 +   0); hi = *(const int4*)(ap1 +  16); MK8(af10, lo, hi)
        lo = *(const int4*)(ap1 +  64); hi = *(const int4*)(ap1 +  80); MK8(af11, lo, hi)
        lo = *(const int4*)(ap1 + 128); hi = *(const int4*)(ap1 + 144); MK8(af12, lo, hi)
        lo = *(const int4*)(ap1 + 192); hi = *(const int4*)(ap1 + 208); MK8(af13, lo, hi)
    }

    f32x16 lv0, lv1, Z, aA0, aA1, aB0, aB1;
#pragma unroll
    for (int r = 0; r < 16; ++r) {
        lv0[r] = -1.0f; lv1[r] = -1.0f;   // compensate the one dummy epilogue
        Z[r] = 0.0f;
        aB0[r] = 0.0f; aB1[r] = 0.0f;     // dummy-epilogue source
    }

    int T0 = seg * NT;

    auto stage = [&](int T, unsigned bufo) {
        const unsigned char* g = B + (size_t)T * (BN * DIM) + (wave * 512 + lane) * 16;
        unsigned lo = bufo + (unsigned)(wave * 512) * 16;
#pragma unroll
        for (int j = 0; j < 8; ++j) {
            __builtin_amdgcn_global_load_lds(
                (const __attribute__((address_space(1))) unsigned int*)(g + j * 1024),
                (__attribute__((address_space(3))) unsigned int*)&bt[lo + j * 1024],
                16, 0, 0);
        }
    };

    stage(T0, 0);

    for (int tt = 0; tt < NT; tt += 2) {
        // ---- tile tt, buffer 0 ----
        __syncthreads();
        stage(T0 + tt + 1, 32768u);
        UNIT(aA0, aA1, aB0, aB1, 0)              // c=0, sub 0
        UNIT(aB0, aB1, aA0, aA1, 512)            // c=1, sub 0
        UNIT(aA0, aA1, aB0, aB1, 16384)          // c=0, sub 1
        UNIT(aB0, aB1, aA0, aA1, 16384 + 512)    // c=1, sub 1
        // ---- tile tt+1, buffer 1 ----
        __syncthreads();
        if (tt + 2 < NT) stage(T0 + tt + 2, 0u);
        UNIT(aA0, aA1, aB0, aB1, 32768)
        UNIT(aB0, aB1, aA0, aA1, 32768 + 512)
        UNIT(aA0, aA1, aB0, aB1, 32768 + 16384)
        UNIT(aB0, aB1, aA0, aA1, 32768 + 16384 + 512)
    }
    // Final unit's epilogue (last writer was aB)
#pragma unroll
    for (int r = 0; r < 16; ++r) {
        lv0[r] += __builtin_amdgcn_exp2f(aB0[r]);
        lv1[r] += __builtin_amdgcn_exp2f(aB1[r]);
    }

    // Sum across the 32 column-lanes
#pragma unroll
    for (int r = 0; r < 16; ++r) {
        float v0 = lv0[r], v1 = lv1[r];
        v0 += __shfl_xor(v0, 1, 64);  v1 += __shfl_xor(v1, 1, 64);
        v0 += __shfl_xor(v0, 2, 64);  v1 += __shfl_xor(v1, 2, 64);
        v0 += __shfl_xor(v0, 4, 64);  v1 += __shfl_xor(v1, 4, 64);
        v0 += __shfl_xor(v0, 8, 64);  v1 += __shfl_xor(v1, 8, 64);
        v0 += __shfl_xor(v0, 16, 64); v1 += __shfl_xor(v1, 16, 64);
        lv0[r] = v0; lv1[r] = v1;
    }
    if (l31 == 0) {
#pragma unroll
        for (int r = 0; r < 16; ++r) {
            int row0 = rowBase + (r & 3) + 8*(r >> 2) + 4*half;
            lpart[(size_t)seg * NROWS + row0] = lv0[r];
            lpart[(size_t)seg * NROWS + row0 + 32] = lv1[r];
        }
    }
}

// Kernel 3: loss_i = -invT*diag_i + ln2*log2(sum_seg l_part), then mean via atomicAdd.
__global__ __launch_bounds__(256) void reduce_kernel(
    const float* __restrict__ lpart, const float* __restrict__ diag,
    float* __restrict__ out)
{
    __shared__ float sm[4];
    int gtid = blockIdx.x * 256 + threadIdx.x;
    float s = 0.0f;
    for (int row = gtid; row < NROWS; row += 32 * 256) {
        float t = 0.0f;
#pragma unroll
        for (int g = 0; g < SEGS; ++g) t += lpart[(size_t)g * NROWS + row];
        s += LN2f * log2f(t) - INVT * diag[row];
    }
    for (int m = 1; m < 64; m <<= 1) s += __shfl_xor(s, m, 64);
    int wave = threadIdx.x >> 6, lane = threadIdx.x & 63;
    if (lane == 0) sm[wave] = s;
    __syncthreads();
    if (threadIdx.x == 0) {
        float tot = sm[0] + sm[1] + sm[2] + sm[3];
        atomicAdd(out, tot * (1.0f / NROWS));
    }
}

extern "C" void kernel_launch(void* const* d_in, const int* in_sizes, int n_in,
                              void* d_out, int out_size, void* d_ws, size_t ws_size,
                              hipStream_t stream) {
    const float* fl = (const float*)d_in[0];
    const float* fg = (const float*)d_in[1];
    float* out = (float*)d_out;

    char* ws = (char*)d_ws;
    unsigned char* A = (unsigned char*)ws;                         // 16384*256 = 4 MB
    unsigned char* B = A + (size_t)NROWS * DIM;                    // 4 MB (staging layout)
    float* diag  = (float*)(ws + 2 * (size_t)NROWS * DIM);         // 64 KB
    float* lpart = diag + NROWS;                                   // SEGS*N*4 = 512 KB

    norm_diag_kernel<<<NROWS / 4, 256, 0, stream>>>(fl, fg, A, B, diag, out);
    sim_lse_kernel<<<dim3(SEGS, NROWS / 256), 256, 0, stream>>>(A, B, lpart);
    reduce_kernel<<<32, 256, 0, stream>>>(lpart, diag, out);
}

// Round 15
// 138.912 us; speedup vs baseline: 1.9738x; 1.9738x over previous
//
#include <hip/hip_runtime.h>
#include <hip/hip_bf16.h>

#define NROWS 16384
#define DIM   256
#define SEGS  8
#define BN    128                     // staged tile: 128 cols x 256 k (fp8) = 32 KB
#define NT    ((NROWS / SEGS) / BN)   // 16 tiles per segment
#define INVT  14.285714285714286f
#define C1f   20.60992915555662f      // log2(e)/0.07 ; A is pre-scaled by this
#define LN2f  0.6931471805599453f

typedef __attribute__((ext_vector_type(8)))  int   int8v;    // fp8 A/B fragment (32 bytes)
typedef __attribute__((ext_vector_type(16))) float f32x16;   // 32x32 MFMA accumulator

#define SCALE1 0x7F7F7F7F   // E8M0 = 1.0 in every byte (opsel-proof)

// Kernel 1: L2-normalize (fp32); emit fp8 e4m3 A (row-major, xC1) and fp8 B in the
// LINEAR DMA staging layout (no xor: DMA writes linear, reads contiguous), plus
// exact fp32 diagonal. One wave per row.
// B layout (16B chunks): chunk(col,kcb) = (col>>7)*2048 + ((col>>6)&1)*1024
//                                        + kcb*64 + (col&63)
__global__ __launch_bounds__(256) void norm_diag_kernel(
    const float* __restrict__ fl, const float* __restrict__ fg,
    unsigned char* __restrict__ A, unsigned char* __restrict__ B,
    float* __restrict__ diag, float* __restrict__ out)
{
    int tid  = threadIdx.x;
    int wave = tid >> 6, lane = tid & 63;
    int row  = blockIdx.x * 4 + wave;
    if (blockIdx.x == 0 && tid == 0) out[0] = 0.0f;   // zero accumulator for final atomicAdd

    float4 xl = ((const float4*)(fl + (size_t)row * DIM))[lane];
    float4 xg = ((const float4*)(fg + (size_t)row * DIM))[lane];
    float ssl = xl.x*xl.x + xl.y*xl.y + xl.z*xl.z + xl.w*xl.w;
    float ssg = xg.x*xg.x + xg.y*xg.y + xg.z*xg.z + xg.w*xg.w;
    for (int m = 1; m < 64; m <<= 1) {
        ssl += __shfl_xor(ssl, m, 64);
        ssg += __shfl_xor(ssg, m, 64);
    }
    float il = 1.0f / fmaxf(sqrtf(ssl), 1e-12f);
    float ig = 1.0f / fmaxf(sqrtf(ssg), 1e-12f);
    float nl0 = xl.x*il, nl1 = xl.y*il, nl2 = xl.z*il, nl3 = xl.w*il;
    float ng0 = xg.x*ig, ng1 = xg.y*ig, ng2 = xg.z*ig, ng3 = xg.w*ig;

    int pa = __builtin_amdgcn_cvt_pk_fp8_f32(nl0 * C1f, nl1 * C1f, 0, false);
    pa     = __builtin_amdgcn_cvt_pk_fp8_f32(nl2 * C1f, nl3 * C1f, pa, true);
    int pb = __builtin_amdgcn_cvt_pk_fp8_f32(ng0, ng1, 0, false);
    pb     = __builtin_amdgcn_cvt_pk_fp8_f32(ng2, ng3, pb, true);
    ((int*)(A + (size_t)row * DIM))[lane] = pa;   // A row-major

    {   // B in linear staging layout
        int kcb = lane >> 2;          // 16B chunk along K (0..15)
        int b4  = lane & 3;           // dword within chunk
        unsigned chunk = (unsigned)((row >> 7) * 2048 + ((row >> 6) & 1) * 1024
                                    + kcb * 64 + (row & 63));
        ((int*)B)[chunk * 4 + b4] = pb;
    }

    float d = nl0*ng0 + nl1*ng1 + nl2*ng2 + nl3*ng3;   // exact fp32 diagonal
    for (int m = 1; m < 64; m <<= 1) d += __shfl_xor(d, m, 64);
    if (lane == 0) diag[row] = d;
}

// Kernel 2: fused sim-GEMM + fixed-max sumexp, MX-fp8 32x32x64.
// R10 frame (DMA prefetch, one barrier/tile, ping-pong acc, deferred epilogue;
// 69.4 us proven) + two register-neutral changes:
//  1. de-XORed LDS: each unit = 1 v_add base + 8 ds_read with 16-bit immediates
//  2. wave phase-stagger: odd waves traverse units in order 2,3,0,1 so their
//     exp2 epilogues overlap even waves' MFMA chains (breaks barrier phase-lock)
__global__ __launch_bounds__(256, 2) void sim_lse_kernel(
    const unsigned char* __restrict__ A, const unsigned char* __restrict__ B,
    float* __restrict__ lpart)
{
    __shared__ __align__(16) unsigned char bt[2 * BN * DIM];   // 2 x 32 KB double buffer

    int tid  = threadIdx.x;
    int lane = tid & 63;
    int l31  = lane & 31, half = lane >> 5;
    int wave = tid >> 6;
    int seg  = blockIdx.x;
    int rowBase = blockIdx.y * 256 + wave * 64;

    // LDS read base: addr = vb + bufo + (unit/chunk immediates)
    unsigned vb = (unsigned)(l31 * 16 + half * 2048);

    // Preload A fragments: lane(l31,half) holds A[m=l31][k = kk*64 + half*32 + 0..31]
    int8v af[2][4];
#pragma unroll
    for (int s = 0; s < 2; ++s) {
        const unsigned char* ap = A + (size_t)(rowBase + s*32 + l31) * DIM + half * 32;
#pragma unroll
        for (int kk = 0; kk < 4; ++kk) {
            int4 lo = *(const int4*)(ap + kk * 64);
            int4 hi = *(const int4*)(ap + kk * 64 + 16);
            int8v v;
            v[0]=lo.x; v[1]=lo.y; v[2]=lo.z; v[3]=lo.w;
            v[4]=hi.x; v[5]=hi.y; v[6]=hi.z; v[7]=hi.w;
            af[s][kk] = v;
        }
    }

    f32x16 lv[2];
    f32x16 Z;
    f32x16 accA[2], accB[2];
#pragma unroll
    for (int r = 0; r < 16; ++r) {
        lv[0][r] = -1.0f; lv[1][r] = -1.0f;   // compensate the one dummy epilogue
        Z[r] = 0.0f;
        accB[0][r] = 0.0f; accB[1][r] = 0.0f; // dummy-epilogue source
    }

    int T0 = seg * NT;

    auto stage = [&](int T, unsigned bufo) {
        const unsigned char* g = B + (size_t)T * (BN * DIM) + (wave * 512 + lane) * 16;
        unsigned lo = bufo + (unsigned)(wave * 512) * 16;
#pragma unroll
        for (int j = 0; j < 8; ++j) {
            __builtin_amdgcn_global_load_lds(
                (const __attribute__((address_space(1))) unsigned int*)(g + j * 1024),
                (__attribute__((address_space(3))) unsigned int*)&bt[lo + j * 1024],
                16, 0, 0);
        }
    };

    // 8 ds_read_b128 (immediate offsets off a single base) + 8 MFMAs, one 64x32 unit.
    // offc is a literal at every call site -> folds into the ds_read immediate.
    auto chain = [&](f32x16 (&ac)[2], unsigned ab, unsigned offc) {
        int8v bf[4];
#pragma unroll
        for (int kk = 0; kk < 4; ++kk) {
            int4 lo = *(const int4*)&bt[ab + offc + (unsigned)kk * 4096u];
            int4 hi = *(const int4*)&bt[ab + offc + (unsigned)kk * 4096u + 1024u];
            int8v v;
            v[0]=lo.x; v[1]=lo.y; v[2]=lo.z; v[3]=lo.w;
            v[4]=hi.x; v[5]=hi.y; v[6]=hi.z; v[7]=hi.w;
            bf[kk] = v;
        }
        ac[0] = __builtin_amdgcn_mfma_scale_f32_32x32x64_f8f6f4(
            af[0][0], bf[0], Z, 0, 0, 0, SCALE1, 0, SCALE1);
        ac[1] = __builtin_amdgcn_mfma_scale_f32_32x32x64_f8f6f4(
            af[1][0], bf[0], Z, 0, 0, 0, SCALE1, 0, SCALE1);
#pragma unroll
        for (int kk = 1; kk < 4; ++kk) {
            ac[0] = __builtin_amdgcn_mfma_scale_f32_32x32x64_f8f6f4(
                af[0][kk], bf[kk], ac[0], 0, 0, 0, SCALE1, 0, SCALE1);
            ac[1] = __builtin_amdgcn_mfma_scale_f32_32x32x64_f8f6f4(
                af[1][kk], bf[kk], ac[1], 0, 0, 0, SCALE1, 0, SCALE1);
        }
    };

    auto epi = [&](f32x16 (&ac)[2]) {
#pragma unroll
        for (int s = 0; s < 2; ++s) {
            f32x16 e;
#pragma unroll
            for (int r = 0; r < 16; ++r)
                e[r] = __builtin_amdgcn_exp2f(ac[s][r]);
            lv[s] += e;
        }
    };

    stage(T0, 0);
    bool odd = (wave & 1) != 0;

    for (int t = 0; t < NT; ++t) {
        unsigned bufo = (t & 1) ? (unsigned)(BN * DIM) : 0u;
        __syncthreads();   // drains own tile-t DMA (in flight a full tile), syncs waves

        if (t + 1 < NT)
            stage(T0 + t + 1, (t & 1) ? 0u : (unsigned)(BN * DIM));

        unsigned ab = vb + bufo;   // single VALU add per tile; all reads imm-offset
        if (!odd) {
            // units 0,1,2,3: offsets {0, 512, 16384, 16896}
            chain(accA, ab, 0u);      epi(accB);
            chain(accB, ab, 512u);    epi(accA);
            chain(accA, ab, 16384u);  epi(accB);
            chain(accB, ab, 16896u);  epi(accA);
        } else {
            // units 2,3,0,1 -- phase-shifted vs even waves (sum is commutative)
            chain(accA, ab, 16384u);  epi(accB);
            chain(accB, ab, 16896u);  epi(accA);
            chain(accA, ab, 0u);      epi(accB);
            chain(accB, ab, 512u);    epi(accA);
        }
    }
    epi(accB);   // final unit

    // Sum across the 32 column-lanes
#pragma unroll
    for (int s = 0; s < 2; ++s)
#pragma unroll
        for (int r = 0; r < 16; ++r) {
            float v = lv[s][r];
            v += __shfl_xor(v, 1, 64);
            v += __shfl_xor(v, 2, 64);
            v += __shfl_xor(v, 4, 64);
            v += __shfl_xor(v, 8, 64);
            v += __shfl_xor(v, 16, 64);
            lv[s][r] = v;
        }
    if (l31 == 0) {
#pragma unroll
        for (int s = 0; s < 2; ++s)
#pragma unroll
            for (int r = 0; r < 16; ++r) {
                int row = rowBase + s*32 + (r & 3) + 8*(r >> 2) + 4*half;
                lpart[(size_t)seg * NROWS + row] = lv[s][r];
            }
    }
}

// Kernel 3: loss_i = -invT*diag_i + ln2*log2(sum_seg l_part), then mean via atomicAdd.
__global__ __launch_bounds__(256) void reduce_kernel(
    const float* __restrict__ lpart, const float* __restrict__ diag,
    float* __restrict__ out)
{
    __shared__ float sm[4];
    int gtid = blockIdx.x * 256 + threadIdx.x;
    float s = 0.0f;
    for (int row = gtid; row < NROWS; row += 32 * 256) {
        float t = 0.0f;
#pragma unroll
        for (int g = 0; g < SEGS; ++g) t += lpart[(size_t)g * NROWS + row];
        s += LN2f * log2f(t) - INVT * diag[row];
    }
    for (int m = 1; m < 64; m <<= 1) s += __shfl_xor(s, m, 64);
    int wave = threadIdx.x >> 6, lane = threadIdx.x & 63;
    if (lane == 0) sm[wave] = s;
    __syncthreads();
    if (threadIdx.x == 0) {
        float tot = sm[0] + sm[1] + sm[2] + sm[3];
        atomicAdd(out, tot * (1.0f / NROWS));
    }
}

extern "C" void kernel_launch(void* const* d_in, const int* in_sizes, int n_in,
                              void* d_out, int out_size, void* d_ws, size_t ws_size,
                              hipStream_t stream) {
    const float* fl = (const float*)d_in[0];
    const float* fg = (const float*)d_in[1];
    float* out = (float*)d_out;

    char* ws = (char*)d_ws;
    unsigned char* A = (unsigned char*)ws;                         // 16384*256 = 4 MB
    unsigned char* B = A + (size_t)NROWS * DIM;                    // 4 MB (staging layout)
    float* diag  = (float*)(ws + 2 * (size_t)NROWS * DIM);         // 64 KB
    float* lpart = diag + NROWS;                                   // SEGS*N*4 = 512 KB

    norm_diag_kernel<<<NROWS / 4, 256, 0, stream>>>(fl, fg, A, B, diag, out);
    sim_lse_kernel<<<dim3(SEGS, NROWS / 256), 256, 0, stream>>>(A, B, lpart);
    reduce_kernel<<<32, 256, 0, stream>>>(lpart, diag, out);
}